// Round 1
// baseline (61.865 us; speedup 1.0000x reference)
//
#include <hip/hip_runtime.h>

// RoiAlign on FPN pyramid.
// Output: (1, N, 14, 14, 256) fp32.  N = 512 in the bench.
// Mapping: block = 256 threads = 4 waves; wave handles one (box, y, x)
// position; lane handles 4 channels (float4). Grid = N * 49.

#define CROP 14
#define POS (CROP * CROP)        // 196
#define C 256
#define CANON 224.0f
#define EPSF 1e-7f

__global__ __launch_bounds__(256) void roi_align_kernel(
    const int* __restrict__ image_shape,
    const float* __restrict__ boxes,
    const float* __restrict__ f0,
    const float* __restrict__ f1,
    const float* __restrict__ f2,
    const float* __restrict__ f3,
    const float* __restrict__ f4,
    float* __restrict__ out)
{
    const int blk  = blockIdx.x;
    const int box  = blk / 49;
    const int quad = blk % 49;
    const int wave = threadIdx.x >> 6;
    const int lane = threadIdx.x & 63;
    const int p    = quad * 4 + wave;       // 0..195
    const int py   = p / CROP;
    const int px   = p % CROP;

    const float imgh = (float)image_shape[1];
    const float imgw = (float)image_shape[2];

    const float bx1 = boxes[box * 4 + 0];
    const float by1 = boxes[box * 4 + 1];
    const float bx2 = boxes[box * 4 + 2];
    const float by2 = boxes[box * 4 + 3];

    // level selection (reference: floor(1 + log2(sqrt(w*h)/224 + eps)), clip [0,4])
    const float w  = bx2 - bx1;
    const float h  = by2 - by1;
    const float sz = sqrtf(w * h);
    float lvf = floorf(1.0f + log2f(sz / CANON + EPSF));
    lvf = fminf(fmaxf(lvf, 0.0f), 4.0f);
    const int lv = (int)lvf;

    const int   s  = 256 >> lv;
    const float fh = (float)s;
    const float fw = (float)s;

    // normalized box, columns [y1', x1', y2', x2'] per reference
    const float ny1 = by1 / imgh * fh / (fh - 1.0f);
    const float nx1 = bx1 / imgw * fw / (fw - 1.0f);
    const float ny2 = (by2 / imgh * fh - 1.0f) / (fh - 1.0f);
    const float nx2 = (bx2 / imgw * fw - 1.0f) / (fw - 1.0f);

    const float ty = (float)py / (float)(CROP - 1);
    const float tx = (float)px / (float)(CROP - 1);

    const float yc = (ny1 * (1.0f - ty) + ny2 * ty) * (fh - 1.0f);
    const float xc = (nx1 * (1.0f - tx) + nx2 * tx) * (fw - 1.0f);

    // corners: clip in float, then cast (matches jnp.clip(...).astype(int32))
    const float ylo = floorf(yc);
    const float fy  = yc - ylo;
    const int y0  = (int)fminf(fmaxf(ylo,        0.0f), fh - 1.0f);
    const int y1i = (int)fminf(fmaxf(ylo + 1.0f, 0.0f), fh - 1.0f);
    const bool vy = (yc >= 0.0f) && (yc <= fh - 1.0f);

    const float xlo = floorf(xc);
    const float fx  = xc - xlo;
    const int x0  = (int)fminf(fmaxf(xlo,        0.0f), fw - 1.0f);
    const int x1i = (int)fminf(fmaxf(xlo + 1.0f, 0.0f), fw - 1.0f);
    const bool vx = (xc >= 0.0f) && (xc <= fw - 1.0f);

    const float* __restrict__ f =
        (lv == 0) ? f0 : (lv == 1) ? f1 : (lv == 2) ? f2 : (lv == 3) ? f3 : f4;

    const int cbase = lane * 4;  // 4 channels per lane
    const size_t otl = ((size_t)y0  * s + x0 ) * C + cbase;
    const size_t otr = ((size_t)y0  * s + x1i) * C + cbase;
    const size_t obl = ((size_t)y1i * s + x0 ) * C + cbase;
    const size_t obr = ((size_t)y1i * s + x1i) * C + cbase;

    float4 rtl = *(const float4*)(f + otl);
    float4 rtr = *(const float4*)(f + otr);
    float4 rbl = *(const float4*)(f + obl);
    float4 rbr = *(const float4*)(f + obr);

    float4 o;
    if (vy && vx) {
        float top, bot;
        top = rtl.x + (rtr.x - rtl.x) * fx;
        bot = rbl.x + (rbr.x - rbl.x) * fx;
        o.x = top + (bot - top) * fy;
        top = rtl.y + (rtr.y - rtl.y) * fx;
        bot = rbl.y + (rbr.y - rbl.y) * fx;
        o.y = top + (bot - top) * fy;
        top = rtl.z + (rtr.z - rtl.z) * fx;
        bot = rbl.z + (rbr.z - rbl.z) * fx;
        o.z = top + (bot - top) * fy;
        top = rtl.w + (rtr.w - rtl.w) * fx;
        bot = rbl.w + (rbr.w - rbl.w) * fx;
        o.w = top + (bot - top) * fy;
    } else {
        o.x = 0.0f; o.y = 0.0f; o.z = 0.0f; o.w = 0.0f;
    }

    *(float4*)(out + ((size_t)box * POS + p) * C + cbase) = o;
}

extern "C" void kernel_launch(void* const* d_in, const int* in_sizes, int n_in,
                              void* d_out, int out_size, void* d_ws, size_t ws_size,
                              hipStream_t stream) {
    const int*   image_shape = (const int*)d_in[0];
    const float* boxes       = (const float*)d_in[1];
    // d_in[2] = scores (unused by the reference output)
    const float* f0 = (const float*)d_in[3];
    const float* f1 = (const float*)d_in[4];
    const float* f2 = (const float*)d_in[5];
    const float* f3 = (const float*)d_in[6];
    const float* f4 = (const float*)d_in[7];
    float* out = (float*)d_out;

    const int N = in_sizes[1] / 4;  // boxes: (1, N, 4)

    dim3 grid(N * 49);
    dim3 block(256);
    roi_align_kernel<<<grid, block, 0, stream>>>(
        image_shape, boxes, f0, f1, f2, f3, f4, out);
}

// Round 2
// 53.046 us; speedup vs baseline: 1.1662x; 1.1662x over previous
//
#include <hip/hip_runtime.h>

// RoiAlign on FPN pyramid.
// Output: (1, N, 14, 14, 256) fp32.  N = 512 in the bench.
// R1: XCD-aware bijective block swizzle (box-contiguous chunks per XCD L2)
//     + 2 positions per wave (8 in-flight float4 loads -> 2x MLP).
// Block = 256 threads = 4 waves; wave handles two (box,y,x) positions;
// lane handles 4 channels (float4). 8 positions/block -> 25 blocks/box.

#define CROP 14
#define POS (CROP * CROP)        // 196
#define C 256
#define CANON 224.0f
#define EPSF 1e-7f
#define BLK_PER_BOX 25           // ceil(196 / 8)

__global__ __launch_bounds__(256) void roi_align_kernel(
    const int* __restrict__ image_shape,
    const float* __restrict__ boxes,
    const float* __restrict__ f0,
    const float* __restrict__ f1,
    const float* __restrict__ f2,
    const float* __restrict__ f3,
    const float* __restrict__ f4,
    float* __restrict__ out)
{
    // ---- bijective XCD swizzle: hw xcd = blockIdx.x % 8; give each XCD a
    // contiguous chunk of logical blocks so one box's blocks share one L2.
    const int nwg = gridDim.x;
    const int q = nwg >> 3, r = nwg & 7;
    const int xcd = blockIdx.x & 7, slot = blockIdx.x >> 3;
    const int blk = (xcd < r ? xcd * (q + 1) : r * (q + 1) + (xcd - r) * q) + slot;

    const int box      = blk / BLK_PER_BOX;
    const int blkInBox = blk % BLK_PER_BOX;
    const int wave = threadIdx.x >> 6;
    const int lane = threadIdx.x & 63;
    const int p0 = blkInBox * 8 + wave * 2;   // 0..198
    const int p1 = p0 + 1;

    const float imgh = (float)image_shape[1];
    const float imgw = (float)image_shape[2];

    const float bx1 = boxes[box * 4 + 0];
    const float by1 = boxes[box * 4 + 1];
    const float bx2 = boxes[box * 4 + 2];
    const float by2 = boxes[box * 4 + 3];

    // level selection (reference: floor(1 + log2(sqrt(w*h)/224 + eps)), clip [0,4])
    const float w  = bx2 - bx1;
    const float h  = by2 - by1;
    const float sz = sqrtf(w * h);
    float lvf = floorf(1.0f + log2f(sz / CANON + EPSF));
    lvf = fminf(fmaxf(lvf, 0.0f), 4.0f);
    const int lv = (int)lvf;

    const int   s  = 256 >> lv;
    const float fh = (float)s;
    const float fw = (float)s;

    // normalized box, columns [y1', x1', y2', x2'] per reference
    const float ny1 = by1 / imgh * fh / (fh - 1.0f);
    const float nx1 = bx1 / imgw * fw / (fw - 1.0f);
    const float ny2 = (by2 / imgh * fh - 1.0f) / (fh - 1.0f);
    const float nx2 = (bx2 / imgw * fw - 1.0f) / (fw - 1.0f);

    const float* __restrict__ f =
        (lv == 0) ? f0 : (lv == 1) ? f1 : (lv == 2) ? f2 : (lv == 3) ? f3 : f4;

    const int cbase = lane * 4;  // 4 channels per lane

    // ---- per-position sampling parameters
    float fxA, fyA, fxB, fyB;
    bool  vA, vB;
    size_t aTL, aTR, aBL, aBR, bTL, bTR, bBL, bBR;

    #pragma unroll
    for (int k = 0; k < 2; ++k) {
        const int p  = k ? p1 : p0;
        const int py = p / CROP;
        const int px = p % CROP;
        const float ty = (float)py / (float)(CROP - 1);
        const float tx = (float)px / (float)(CROP - 1);
        const float yc = (ny1 * (1.0f - ty) + ny2 * ty) * (fh - 1.0f);
        const float xc = (nx1 * (1.0f - tx) + nx2 * tx) * (fw - 1.0f);

        const float ylo = floorf(yc);
        const float fy  = yc - ylo;
        const int y0  = (int)fminf(fmaxf(ylo,        0.0f), fh - 1.0f);
        const int y1i = (int)fminf(fmaxf(ylo + 1.0f, 0.0f), fh - 1.0f);
        const bool vy = (yc >= 0.0f) && (yc <= fh - 1.0f);

        const float xlo = floorf(xc);
        const float fx  = xc - xlo;
        const int x0  = (int)fminf(fmaxf(xlo,        0.0f), fw - 1.0f);
        const int x1i = (int)fminf(fmaxf(xlo + 1.0f, 0.0f), fw - 1.0f);
        const bool vx = (xc >= 0.0f) && (xc <= fw - 1.0f);

        const size_t tl = ((size_t)y0  * s + x0 ) * C + cbase;
        const size_t tr = ((size_t)y0  * s + x1i) * C + cbase;
        const size_t bl = ((size_t)y1i * s + x0 ) * C + cbase;
        const size_t br = ((size_t)y1i * s + x1i) * C + cbase;
        if (k == 0) { fxA=fx; fyA=fy; vA=vy&&vx; aTL=tl; aTR=tr; aBL=bl; aBR=br; }
        else        { fxB=fx; fyB=fy; vB=vy&&vx; bTL=tl; bTR=tr; bBL=bl; bBR=br; }
    }

    const bool doA = (p0 < POS);
    const bool doB = (p1 < POS);

    // ---- issue all 8 loads (guarded; clamp addr for inactive to 0)
    float4 rA0, rA1, rA2, rA3, rB0, rB1, rB2, rB3;
    if (doA) {
        rA0 = *(const float4*)(f + aTL);
        rA1 = *(const float4*)(f + aTR);
        rA2 = *(const float4*)(f + aBL);
        rA3 = *(const float4*)(f + aBR);
    }
    if (doB) {
        rB0 = *(const float4*)(f + bTL);
        rB1 = *(const float4*)(f + bTR);
        rB2 = *(const float4*)(f + bBL);
        rB3 = *(const float4*)(f + bBR);
    }

    // ---- combine + store
    if (doA) {
        float4 o;
        if (vA) {
            float top, bot;
            top = rA0.x + (rA1.x - rA0.x) * fxA; bot = rA2.x + (rA3.x - rA2.x) * fxA; o.x = top + (bot - top) * fyA;
            top = rA0.y + (rA1.y - rA0.y) * fxA; bot = rA2.y + (rA3.y - rA2.y) * fxA; o.y = top + (bot - top) * fyA;
            top = rA0.z + (rA1.z - rA0.z) * fxA; bot = rA2.z + (rA3.z - rA2.z) * fxA; o.z = top + (bot - top) * fyA;
            top = rA0.w + (rA1.w - rA0.w) * fxA; bot = rA2.w + (rA3.w - rA2.w) * fxA; o.w = top + (bot - top) * fyA;
        } else { o.x = o.y = o.z = o.w = 0.0f; }
        *(float4*)(out + ((size_t)box * POS + p0) * C + cbase) = o;
    }
    if (doB) {
        float4 o;
        if (vB) {
            float top, bot;
            top = rB0.x + (rB1.x - rB0.x) * fxB; bot = rB2.x + (rB3.x - rB2.x) * fxB; o.x = top + (bot - top) * fyB;
            top = rB0.y + (rB1.y - rB0.y) * fxB; bot = rB2.y + (rB3.y - rB2.y) * fxB; o.y = top + (bot - top) * fyB;
            top = rB0.z + (rB1.z - rB0.z) * fxB; bot = rB2.z + (rB3.z - rB2.z) * fxB; o.z = top + (bot - top) * fyB;
            top = rB0.w + (rB1.w - rB0.w) * fxB; bot = rB2.w + (rB3.w - rB2.w) * fxB; o.w = top + (bot - top) * fyB;
        } else { o.x = o.y = o.z = o.w = 0.0f; }
        *(float4*)(out + ((size_t)box * POS + p1) * C + cbase) = o;
    }
}

extern "C" void kernel_launch(void* const* d_in, const int* in_sizes, int n_in,
                              void* d_out, int out_size, void* d_ws, size_t ws_size,
                              hipStream_t stream) {
    const int*   image_shape = (const int*)d_in[0];
    const float* boxes       = (const float*)d_in[1];
    // d_in[2] = scores (unused by the reference output)
    const float* f0 = (const float*)d_in[3];
    const float* f1 = (const float*)d_in[4];
    const float* f2 = (const float*)d_in[5];
    const float* f3 = (const float*)d_in[6];
    const float* f4 = (const float*)d_in[7];
    float* out = (float*)d_out;

    const int N = in_sizes[1] / 4;  // boxes: (1, N, 4)

    dim3 grid(N * BLK_PER_BOX);
    dim3 block(256);
    roi_align_kernel<<<grid, block, 0, stream>>>(
        image_shape, boxes, f0, f1, f2, f3, f4, out);
}